// Round 13
// baseline (872.509 us; speedup 1.0000x reference)
//
#include <hip/hip_runtime.h>
#include <hip/hip_bf16.h>
#include <math.h>

// Problem constants
#define NTOK   8192
#define DMODEL 2048
#define NEXP   8
#define RGATE  8
#define DFF    1024

#define NEG_SENTINEL (-3.0e38f)

using f32x4  = __attribute__((ext_vector_type(4))) float;
using short8 = __attribute__((ext_vector_type(8))) short;

// RNE float->bf16
static __device__ __forceinline__ short f2bf(float f) {
  union { float f; unsigned u; } v; v.f = f;
  unsigned r = v.u + 0x7fffu + ((v.u >> 16) & 1u);
  return (short)(r >> 16);
}
static __device__ __forceinline__ float bf2f(short s) {
  union { unsigned u; float f; } v; v.u = ((unsigned)(unsigned short)s) << 16;
  return v.f;
}
static __device__ __forceinline__ short8 cvt8(const float4 a, const float4 b) {
  short8 o;
  o[0] = f2bf(a.x); o[1] = f2bf(a.y); o[2] = f2bf(a.z); o[3] = f2bf(a.w);
  o[4] = f2bf(b.x); o[5] = f2bf(b.y); o[6] = f2bf(b.z); o[7] = f2bf(b.w);
  return o;
}

#define GLOAD_LDS(gp, lp)                                                  \
  __builtin_amdgcn_global_load_lds(                                        \
      (const __attribute__((address_space(1))) void*)(gp),                 \
      (__attribute__((address_space(3))) void*)(lp), 16, 0, 0)

// Counted-wait barrier macros (T4). vmcnt(8): keep the newer 8 global_load_lds
// in flight; wait only the older stage. lgkmcnt(0)+barrier = "all waves done
// reading this buffer" (every ds_read is consumed by an MFMA before the
// barrier, so per-wave LDS reads are complete). sched_barrier(0) pins order
// around the inline asm (rule #18).
#define VM8_BARRIER()                                                      \
  asm volatile("s_waitcnt vmcnt(8)" ::: "memory");                         \
  __builtin_amdgcn_sched_barrier(0);                                       \
  __builtin_amdgcn_s_barrier();                                            \
  __builtin_amdgcn_sched_barrier(0)
#define VM0_BARRIER()                                                      \
  asm volatile("s_waitcnt vmcnt(0)" ::: "memory");                         \
  __builtin_amdgcn_sched_barrier(0);                                       \
  __builtin_amdgcn_s_barrier();                                            \
  __builtin_amdgcn_sched_barrier(0)
#define LGKM_BARRIER()                                                     \
  asm volatile("s_waitcnt lgkmcnt(0)" ::: "memory");                       \
  __builtin_amdgcn_sched_barrier(0);                                       \
  __builtin_amdgcn_s_barrier();                                            \
  __builtin_amdgcn_sched_barrier(0)

// ---------------------------------------------------------------------------
// prep_all: ONE kernel for {zero cnt, cvt x->xb, cvt wd->wdb, pack wg/wu->wgu,
// optional out zero}.
// ---------------------------------------------------------------------------
#define SEG_CVT  2097152              // CNT/8 16B-chunk count
#define SEG_PACK 4194304              // NEXP*2048*(DMODEL/8)
__global__ __launch_bounds__(256) void prep_all(
    const float* __restrict__ x, const float* __restrict__ wd,
    const float* __restrict__ wg, const float* __restrict__ wu,
    short* __restrict__ xb, short* __restrict__ wdb, short* __restrict__ wgu,
    int* __restrict__ cnt, float4* __restrict__ out4, int zero_out) {
  if (blockIdx.x == 0 && threadIdx.x < 16) cnt[threadIdx.x] = 0;
  const int stride = gridDim.x * blockDim.x;
  const int total = SEG_CVT * 2 + SEG_PACK + (zero_out ? SEG_CVT : 0);
  for (int i = blockIdx.x * blockDim.x + threadIdx.x; i < total; i += stride) {
    if (i < SEG_CVT) {
      const float4 a = ((const float4*)x)[(size_t)i * 2];
      const float4 b = ((const float4*)x)[(size_t)i * 2 + 1];
      ((short8*)xb)[i] = cvt8(a, b);
    } else if (i < 2 * SEG_CVT) {
      const int j = i - SEG_CVT;
      const float4 a = ((const float4*)wd)[(size_t)j * 2];
      const float4 b = ((const float4*)wd)[(size_t)j * 2 + 1];
      ((short8*)wdb)[j] = cvt8(a, b);
    } else if (i < 2 * SEG_CVT + SEG_PACK) {
      const int j = i - 2 * SEG_CVT;
      const int c = j & 255;
      const int r = (j >> 8) & 2047;
      const int e = j >> 19;
      const int sel = (r >> 4) & 1;
      const int f = ((r >> 5) << 4) + (r & 15);
      const float* src = (sel ? wu : wg) + ((size_t)(e * DFF + f)) * DMODEL + c * 8;
      const float4 a = *(const float4*)src;
      const float4 b = *(const float4*)(src + 4);
      ((short8*)wgu)[j] = cvt8(a, b);
    } else {
      const int j = i - (2 * SEG_CVT + SEG_PACK);
      out4[(size_t)j * 2] = make_float4(0.f, 0.f, 0.f, 0.f);
      out4[(size_t)j * 2 + 1] = make_float4(0.f, 0.f, 0.f, 0.f);
    }
  }
}

// ---------------------------------------------------------------------------
// gate_v3: register outer-product gate + pos[e][n] inverse map (R10-proven).
// ---------------------------------------------------------------------------
__global__ __launch_bounds__(256) void gate_v3(
    const float* __restrict__ x, const float* __restrict__ W_A,
    const float* __restrict__ gscale, const float* __restrict__ gbias,
    float* __restrict__ gw, float* __restrict__ score_out,
    int* __restrict__ idx, int* __restrict__ pos, int* __restrict__ cnt) {
  __shared__ float ghs[32][65];
  const int tok0 = blockIdx.x * 32;
  const int t = threadIdx.x;
  const int ks = t & 3;
  const int posn = t >> 2;
  const int tg = posn & 7;
  const int rg = posn >> 3;
  const float* xp = x + (size_t)(tok0 + tg * 4) * DMODEL;
  const float* wp = W_A + (size_t)(rg * 8) * DMODEL;

  float acc[4][8];
#pragma unroll
  for (int i = 0; i < 4; ++i)
#pragma unroll
    for (int r = 0; r < 8; ++r) acc[i][r] = 0.f;

  float4 xa_[4], wa_[8], xb_[4], wb_[8];
  auto loadj = [&](int j, float4* xv, float4* wv) {
    const int k = ks * 4 + j * 16;
#pragma unroll
    for (int i = 0; i < 4; ++i) xv[i] = *(const float4*)(xp + (size_t)i * DMODEL + k);
#pragma unroll
    for (int r = 0; r < 8; ++r) wv[r] = *(const float4*)(wp + (size_t)r * DMODEL + k);
  };
  auto fmaj = [&](const float4* xv, const float4* wv) {
#pragma unroll
    for (int i = 0; i < 4; ++i)
#pragma unroll
      for (int r = 0; r < 8; ++r) {
        acc[i][r] = fmaf(xv[i].x, wv[r].x, acc[i][r]);
        acc[i][r] = fmaf(xv[i].y, wv[r].y, acc[i][r]);
        acc[i][r] = fmaf(xv[i].z, wv[r].z, acc[i][r]);
        acc[i][r] = fmaf(xv[i].w, wv[r].w, acc[i][r]);
      }
  };

  loadj(0, xa_, wa_);
#pragma unroll 1
  for (int j = 0; j < 128; j += 2) {
    loadj(j + 1, xb_, wb_);
    fmaj(xa_, wa_);
    if (j + 2 < 128) loadj(j + 2, xa_, wa_);
    fmaj(xb_, wb_);
  }

#pragma unroll
  for (int i = 0; i < 4; ++i)
#pragma unroll
    for (int r = 0; r < 8; ++r) {
      float v = acc[i][r];
      v += __shfl_xor(v, 1);
      v += __shfl_xor(v, 2);
      acc[i][r] = v;
    }
  if (ks == 0) {
#pragma unroll
    for (int i = 0; i < 4; ++i)
#pragma unroll
      for (int r = 0; r < 8; ++r) ghs[tg * 4 + i][rg * 8 + r] = acc[i][r];
  }
  __syncthreads();

  {
    const int tk = t >> 3, e = t & 7;
    const int n = tok0 + tk;
    float ss = 0.f;
#pragma unroll
    for (int r = 0; r < RGATE; ++r) { const float v = ghs[tk][e * 8 + r]; ss += v * v; }
    const float score = sqrtf(ss) * gscale[e] - gbias[e];
    const bool m = (score >= 0.0f);
    const float sig = 1.0f / (1.0f + expf(-score));
    gw[(size_t)n * NEXP + e] = m ? sig : 0.0f;
    score_out[(size_t)n * NEXP + e] = m ? score : NEG_SENTINEL;
    int slot = -1;
    if (m) {
      slot = atomicAdd(&cnt[e], 1);
      idx[(size_t)e * NTOK + slot] = n;
    }
    pos[(size_t)e * NTOK + n] = slot;
  }
}

// ===========================================================================
// ffn1_gemm256: R12 quadrant-phasing/setprio + R13: counted-vmcnt pipeline.
// Staging runs 2 tiles ahead; vmcnt never drains to 0 in the main loop
// (T4). FIFO bookkeeping: each STAGE = exactly 8 gload_lds/wave, so
// vmcnt(8) releases precisely the older stage's buffer.
// ===========================================================================
#define FFN1_STAGE(AS, BS, k0)                                                 \
  _Pragma("unroll") for (int i_ = 0; i_ < 4; ++i_) {                           \
    const int row_ = wid * 32 + i_ * 8;                                        \
    GLOAD_LDS(xb + (size_t)tokA[i_] * DMODEL + (k0) + lk,                      \
              (char*)(AS) + row_ * 128);                                       \
    GLOAD_LDS(Bb + (size_t)(row_ + lr) * DMODEL + (k0) + lk,                   \
              (char*)(BS) + row_ * 128);                                       \
  }

#define CSWZ(ks_) ((((ks_) * 4 + (lane >> 4)) ^ (lane & 7)) << 4)

#define FFN1_COMPUTE(AS, BS)                                                   \
  _Pragma("unroll") for (int ah_ = 0; ah_ < 2; ++ah_) {                        \
    short8 af_[4][2];                                                          \
    _Pragma("unroll") for (int q_ = 0; q_ < 4; ++q_)                           \
      _Pragma("unroll") for (int ks_ = 0; ks_ < 2; ++ks_)                      \
        af_[q_][ks_] = *(const short8*)((const char*)(AS) +                    \
            (arow + (ah_ * 4 + q_) * 16 + (lane & 15)) * 128 + CSWZ(ks_));     \
    _Pragma("unroll") for (int bh_ = 0; bh_ < 2; ++bh_) {                      \
      short8 bf_[2][2];                                                        \
      _Pragma("unroll") for (int q_ = 0; q_ < 2; ++q_)                         \
        _Pragma("unroll") for (int ks_ = 0; ks_ < 2; ++ks_)                    \
          bf_[q_][ks_] = *(const short8*)((const char*)(BS) +                  \
              (brow + (bh_ * 2 + q_) * 16 + (lane & 15)) * 128 + CSWZ(ks_));   \
      __builtin_amdgcn_s_setprio(1);                                           \
      _Pragma("unroll") for (int ks_ = 0; ks_ < 2; ++ks_)                      \
        _Pragma("unroll") for (int nf_ = 0; nf_ < 4; ++nf_)                    \
          _Pragma("unroll") for (int ff_ = 0; ff_ < 2; ++ff_)                  \
            acc[ah_ * 4 + nf_][bh_ * 2 + ff_] =                                \
                __builtin_amdgcn_mfma_f32_16x16x32_bf16(                       \
                    af_[nf_][ks_], bf_[ff_][ks_],                              \
                    acc[ah_ * 4 + nf_][bh_ * 2 + ff_], 0, 0, 0);               \
      __builtin_amdgcn_s_setprio(0);                                           \
    }                                                                          \
  }

__global__ __launch_bounds__(512, 2) void ffn1_gemm256(
    const short* __restrict__ xb, const short* __restrict__ wgu,
    const int* __restrict__ idx, const int* __restrict__ cnt,
    const float* __restrict__ gw, short* __restrict__ Hb, int e_arg) {
  const int e = (e_arg < 0) ? (int)blockIdx.z : e_arg;
  short* __restrict__ Hbe = Hb + ((e_arg < 0) ? (size_t)e * NTOK * DFF : (size_t)0);
  const int cnte = cnt[e];
  const int n0 = blockIdx.y * 256;
  if (n0 >= cnte) return;

  __shared__ __align__(16) short As0[256 * 64];
  __shared__ __align__(16) short Bs0[256 * 64];
  __shared__ __align__(16) short As1[256 * 64];
  __shared__ __align__(16) short Bs1[256 * 64];

  const int c0 = blockIdx.x * 256;
  const int t = threadIdx.x, lane = t & 63, wid = t >> 6;
  const int arow = (wid >> 2) * 128;
  const int brow = (wid & 3) * 64;
  const int* idxe = idx + (size_t)e * NTOK;
  const short* Bb = wgu + (size_t)e * 2048 * DMODEL + (size_t)c0 * DMODEL;
  const int lr = lane >> 3;
  const int lk = ((lane & 7) ^ lr) * 8;

  int tokA[4];
#pragma unroll
  for (int i = 0; i < 4; ++i) {
    int n = n0 + wid * 32 + i * 8 + lr;
    if (n >= cnte) n = cnte - 1;  // idx not pre-zeroed: clamp to valid slot
    tokA[i] = idxe[n];
  }

  f32x4 acc[8][4];
#pragma unroll
  for (int i = 0; i < 8; ++i)
#pragma unroll
    for (int j = 0; j < 4; ++j) acc[i][j] = (f32x4){0.f, 0.f, 0.f, 0.f};

  // Counted-vmcnt pipeline: 2 stages in flight at all times.
  FFN1_STAGE(As0, Bs0, 0);      // tile 0 (8 loads/wave)
  FFN1_STAGE(As1, Bs1, 64);     // tile 1 (8 more)
#pragma unroll 1
  for (int kt = 0; kt < 30; kt += 2) {
    VM8_BARRIER();                         // tile kt ready; kt+1 in flight
    FFN1_COMPUTE(As0, Bs0);
    LGKM_BARRIER();                        // all waves done reading buf0
    FFN1_STAGE(As0, Bs0, (kt + 2) * 64);
    VM8_BARRIER();                         // tile kt+1 ready; kt+2 in flight
    FFN1_COMPUTE(As1, Bs1);
    LGKM_BARRIER();                        // all waves done reading buf1
    FFN1_STAGE(As1, Bs1, (kt + 3) * 64);
  }
  VM8_BARRIER();                           // tile 30 ready
  FFN1_COMPUTE(As0, Bs0);
  VM0_BARRIER();                           // tile 31 ready (tail drain)
  FFN1_COMPUTE(As1, Bs1);

  const int fhalf = c0 >> 1;
#pragma unroll
  for (int nf = 0; nf < 8; ++nf) {
#pragma unroll
    for (int j = 0; j < 4; ++j) {
      const int n = n0 + arow + nf * 16 + (lane >> 4) * 4 + j;
      const bool valid = n < cnte;
      const int tok = valid ? idxe[n] : 0;
      const float gwv = gw[(size_t)tok * NEXP + e];
#pragma unroll
      for (int p = 0; p < 2; ++p) {
        const float gv = acc[nf][2 * p][j];
        const float uv = acc[nf][2 * p + 1][j];
        const float h = (gv / (1.f + expf(-gv))) * uv * gwv;
        const int f = fhalf + ((wid & 3) * 2 + p) * 16 + (lane & 15);
        Hbe[(size_t)n * DFF + f] = valid ? f2bf(h) : (short)0;
      }
    }
  }
}

// ===========================================================================
// ffn2 staging + phased compute (R12-proven form, unchanged this round)
// ===========================================================================
#define FFN2_STAGE(AS, BS, k0)                                                 \
  _Pragma("unroll") for (int i_ = 0; i_ < 4; ++i_) {                           \
    const int row_ = wid * 32 + i_ * 8;                                        \
    GLOAD_LDS(Ab + (size_t)(row_ + lr) * DFF + (k0) + lk,                      \
              (char*)(AS) + row_ * 128);                                       \
    GLOAD_LDS(Bb + (size_t)(row_ + lr) * DFF + (k0) + lk,                      \
              (char*)(BS) + row_ * 128);                                       \
  }

#define FFN2_COMPUTE(AS, BS)                                                   \
  {                                                                            \
    short8 af_[4][2];                                                          \
    _Pragma("unroll") for (int q_ = 0; q_ < 4; ++q_)                           \
      _Pragma("unroll") for (int ks_ = 0; ks_ < 2; ++ks_)                      \
        af_[q_][ks_] = *(const short8*)((const char*)(AS) +                    \
            (wr * 64 + q_ * 16 + (lane & 15)) * 128 + CSWZ(ks_));              \
    _Pragma("unroll") for (int bh_ = 0; bh_ < 2; ++bh_) {                      \
      short8 bf_[2][2];                                                        \
      _Pragma("unroll") for (int q_ = 0; q_ < 2; ++q_)                         \
        _Pragma("unroll") for (int ks_ = 0; ks_ < 2; ++ks_)                    \
          bf_[q_][ks_] = *(const short8*)((const char*)(BS) +                  \
              (wc * 64 + (bh_ * 2 + q_) * 16 + (lane & 15)) * 128 + CSWZ(ks_));\
      __builtin_amdgcn_s_setprio(1);                                           \
      _Pragma("unroll") for (int ks_ = 0; ks_ < 2; ++ks_)                      \
        _Pragma("unroll") for (int nf_ = 0; nf_ < 4; ++nf_)                    \
          _Pragma("unroll") for (int ff_ = 0; ff_ < 2; ++ff_)                  \
            acc[nf_][bh_ * 2 + ff_] =                                          \
                __builtin_amdgcn_mfma_f32_16x16x32_bf16(                       \
                    af_[nf_][ks_], bf_[ff_][ks_],                              \
                    acc[nf_][bh_ * 2 + ff_], 0, 0, 0);                         \
      __builtin_amdgcn_s_setprio(0);                                           \
    }                                                                          \
  }

// ---------------------------------------------------------------------------
// ffn2z_gemm: expert GROUP pass -> bf16 compact partials (R11/R12-proven).
// ---------------------------------------------------------------------------
__global__ __launch_bounds__(256, 2) void ffn2z_gemm(
    const short* __restrict__ Hb, const short* __restrict__ wdb,
    const int* __restrict__ cnt, short* __restrict__ Cp, int e0) {
  const int e = e0 + blockIdx.z;
  const int cnte = cnt[e];
  const int n0 = blockIdx.y * 128;
  if (n0 >= cnte) return;
  __shared__ __align__(16) short As0[128 * 64];
  __shared__ __align__(16) short Bs0[128 * 64];
  __shared__ __align__(16) short As1[128 * 64];
  __shared__ __align__(16) short Bs1[128 * 64];

  const int c0 = blockIdx.x * 128;
  const int t = threadIdx.x, lane = t & 63, wid = t >> 6;
  const int wr = wid >> 1, wc = wid & 1;
  const short* Ab = Hb + (size_t)e * NTOK * DFF + (size_t)n0 * DFF;
  const short* Bb = wdb + (size_t)e * DMODEL * DFF + (size_t)c0 * DFF;
  short* Cpe = Cp + (size_t)blockIdx.z * NTOK * DMODEL;
  const int lr = lane >> 3;
  const int lk = ((lane & 7) ^ lr) * 8;

  f32x4 acc[4][4];
#pragma unroll
  for (int i = 0; i < 4; ++i)
#pragma unroll
    for (int j = 0; j < 4; ++j) acc[i][j] = (f32x4){0.f, 0.f, 0.f, 0.f};

  FFN2_STAGE(As0, Bs0, 0);
  __syncthreads();
#pragma unroll 1
  for (int kt = 0; kt < 16; kt += 2) {
    FFN2_STAGE(As1, Bs1, (kt + 1) * 64);
    FFN2_COMPUTE(As0, Bs0);
    __syncthreads();
    if (kt + 2 < 16) FFN2_STAGE(As0, Bs0, (kt + 2) * 64);
    FFN2_COMPUTE(As1, Bs1);
    __syncthreads();
  }

#pragma unroll
  for (int nf = 0; nf < 4; ++nf) {
#pragma unroll
    for (int j = 0; j < 4; ++j) {
      const int n = n0 + wr * 64 + nf * 16 + (lane >> 4) * 4 + j;
      if (n < cnte) {
#pragma unroll
        for (int ff = 0; ff < 4; ++ff) {
          const int d = c0 + wc * 64 + ff * 16 + (lane & 15);
          Cpe[(size_t)n * DMODEL + d] = f2bf(acc[nf][ff][j]);
        }
      }
    }
  }
}

// ---------------------------------------------------------------------------
// reduce_out_g: out[n,:] (=|+=) sum_{e in group} Cp[z][pos[e][n],:] (R11).
// ---------------------------------------------------------------------------
__global__ __launch_bounds__(256) void reduce_out_g(
    const short* __restrict__ Cp, const int* __restrict__ pos,
    float* __restrict__ out, int e0, int ge, int accum) {
  const int n = blockIdx.x;
  const int t = threadIdx.x;
  float* op = out + (size_t)n * DMODEL + t * 8;
  float acc[8];
  if (accum) {
    const float4 a = *(const float4*)op;
    const float4 b = *(const float4*)(op + 4);
    acc[0] = a.x; acc[1] = a.y; acc[2] = a.z; acc[3] = a.w;
    acc[4] = b.x; acc[5] = b.y; acc[6] = b.z; acc[7] = b.w;
  } else {
#pragma unroll
    for (int j = 0; j < 8; ++j) acc[j] = 0.f;
  }
  for (int el = 0; el < ge; ++el) {
    const int p = pos[(size_t)(e0 + el) * NTOK + n];
    if (p >= 0) {
      const short8 v = *(const short8*)(Cp + (size_t)el * NTOK * DMODEL +
                                        (size_t)p * DMODEL + t * 8);
#pragma unroll
      for (int j = 0; j < 8; ++j) acc[j] += bf2f(v[j]);
    }
  }
  *(float4*)op = make_float4(acc[0], acc[1], acc[2], acc[3]);
  *(float4*)(op + 4) = make_float4(acc[4], acc[5], acc[6], acc[7]);
}

// ---------------------------------------------------------------------------
// ffn2_gemm_db (fallback tiers): out-RMW version (R9-proven).
// ---------------------------------------------------------------------------
__global__ __launch_bounds__(256, 2) void ffn2_gemm_db(
    const short* __restrict__ Hbe, const short* __restrict__ wdb,
    const int* __restrict__ idx, const int* __restrict__ cnt,
    float* __restrict__ out, float* __restrict__ dummy, int e) {
  const int cnte = cnt[e];
  const int n0 = blockIdx.y * 128;
  if (n0 >= cnte) return;
  __shared__ __align__(16) short As0[128 * 64];
  __shared__ __align__(16) short Bs0[128 * 64];
  __shared__ __align__(16) short As1[128 * 64];
  __shared__ __align__(16) short Bs1[128 * 64];

  const int c0 = blockIdx.x * 128;
  const int t = threadIdx.x, lane = t & 63, wid = t >> 6;
  const int wr = wid >> 1, wc = wid & 1;
  const int* idxe = idx + (size_t)e * NTOK;
  const short* Ab = Hbe + (size_t)n0 * DFF;
  const short* Bb = wdb + (size_t)e * DMODEL * DFF + (size_t)c0 * DFF;
  const int lr = lane >> 3;
  const int lk = ((lane & 7) ^ lr) * 8;

  f32x4 acc[4][4];
#pragma unroll
  for (int i = 0; i < 4; ++i)
#pragma unroll
    for (int j = 0; j < 4; ++j) acc[i][j] = (f32x4){0.f, 0.f, 0.f, 0.f};

  FFN2_STAGE(As0, Bs0, 0);
  __syncthreads();
#pragma unroll 1
  for (int kt = 0; kt < 16; kt += 2) {
    FFN2_STAGE(As1, Bs1, (kt + 1) * 64);
    FFN2_COMPUTE(As0, Bs0);
    __syncthreads();
    if (kt + 2 < 16) FFN2_STAGE(As0, Bs0, (kt + 2) * 64);
    FFN2_COMPUTE(As1, Bs1);
    __syncthreads();
  }

#pragma unroll
  for (int nf = 0; nf < 4; ++nf) {
#pragma unroll
    for (int j = 0; j < 4; ++j) {
      const int n = n0 + wr * 64 + nf * 16 + (lane >> 4) * 4 + j;
      const bool valid = n < cnte;
      const int tok = valid ? idxe[n] : 0;
      float* bp = valid ? (out + (size_t)tok * DMODEL) : dummy;
#pragma unroll
      for (int ff = 0; ff < 4; ++ff) {
        const int d = c0 + wc * 64 + ff * 16 + (lane & 15);
        bp[valid ? d : (d & 2047)] += acc[nf][ff][j];
      }
    }
  }
}

// ---------------------------------------------------------------------------
extern "C" void kernel_launch(void* const* d_in, const int* in_sizes, int n_in,
                              void* d_out, int out_size, void* d_ws, size_t ws_size,
                              hipStream_t stream) {
  const float* x      = (const float*)d_in[0];
  const float* W_A    = (const float*)d_in[1];
  const float* gscale = (const float*)d_in[2];
  const float* gbias  = (const float*)d_in[3];
  const float* wg     = (const float*)d_in[4];
  const float* wu     = (const float*)d_in[5];
  const float* wd     = (const float*)d_in[6];

  float* out       = (float*)d_out;                // [N, D]
  float* score_out = out + (size_t)NTOK * DMODEL;  // [N, E]

  // ws layout: gw | idx | pos | cnt | dummy | wdb | Hb(8x) | xb | wgu
  // Tier-C-grouped: Cp (G x 32MB slices) aliases xb+wgu (dead after ffn1).
  const size_t CNT = (size_t)16777216;
  const size_t CP_SLICE = (size_t)NTOK * DMODEL * 2;  // 32 MB
  size_t off = 0;
  float* gw    = (float*)((char*)d_ws + off); off += (size_t)NTOK * NEXP * 4;
  int*   idx   = (int*)((char*)d_ws + off);   off += (size_t)NEXP * NTOK * 4;
  int*   pos   = (int*)((char*)d_ws + off);   off += (size_t)NEXP * NTOK * 4;
  int*   cnt   = (int*)((char*)d_ws + off);   off += 16 * 4;
  float* dummy = (float*)((char*)d_ws + off); off += (size_t)DMODEL * 4;
  short* wdb   = (short*)((char*)d_ws + off); off += CNT * 2;
  const size_t hb_off = off;
  short* Hb    = (short*)((char*)d_ws + off); off += (size_t)NEXP * NTOK * DFF * 2;
  const size_t xb_off = off;
  short* xb    = (short*)((char*)d_ws + off); off += CNT * 2;
  short* wgu   = (short*)((char*)d_ws + off); off += CNT * 4;
  const size_t needA = off;
  short* Cp    = (short*)((char*)d_ws + xb_off);

  const bool tierA = (ws_size >= needA);
  int G = 0;
  if (tierA) {
    size_t avail = ws_size - xb_off;
    G = (int)(avail / CP_SLICE);
    if (G > NEXP) G = NEXP;
  }

  // Tier B layout (shared Hb)
  short* HbB  = Hb;
  short* xbB  = (short*)((char*)d_ws + hb_off + (size_t)NTOK * DFF * 2);
  short* wguB = xbB + CNT;

  const int zero_out = (tierA && G >= 1) ? 0 : 1;
  short* xbT  = tierA ? xb : xbB;
  short* wguT = tierA ? wgu : wguB;

  prep_all<<<2048, 256, 0, stream>>>(x, wd, wg, wu, xbT, wdb, wguT, cnt,
                                     (float4*)out, zero_out);
  gate_v3<<<NTOK / 32, 256, 0, stream>>>(x, W_A, gscale, gbias, gw,
                                         score_out, idx, pos, cnt);

  if (tierA && G >= 1) {
    ffn1_gemm256<<<dim3(2048 / 256, NTOK / 256, NEXP), 512, 0, stream>>>(
        xb, wgu, idx, cnt, gw, Hb, -1);
    const int np = (NEXP + G - 1) / G;
    int e0 = 0;
    for (int p = 0; p < np; ++p) {
      const int rem_p = np - p;
      const int ge = (NEXP - e0 + rem_p - 1) / rem_p;
      ffn2z_gemm<<<dim3(DMODEL / 128, NTOK / 128, ge), 256, 0, stream>>>(
          Hb, wdb, cnt, Cp, e0);
      reduce_out_g<<<NTOK, 256, 0, stream>>>(Cp, pos, out, e0, ge, p > 0);
      e0 += ge;
    }
  } else if (tierA) {
    ffn1_gemm256<<<dim3(2048 / 256, NTOK / 256, NEXP), 512, 0, stream>>>(
        xb, wgu, idx, cnt, gw, Hb, -1);
    for (int e = 0; e < NEXP; ++e)
      ffn2_gemm_db<<<dim3(DMODEL / 128, NTOK / 128), 256, 0, stream>>>(
          Hb + (size_t)e * NTOK * DFF, wdb, idx, cnt, out, dummy, e);
  } else {
    for (int e = 0; e < NEXP; ++e) {
      ffn1_gemm256<<<dim3(2048 / 256, NTOK / 256), 512, 0, stream>>>(
          xbB, wguB, idx, cnt, gw, HbB, e);
      ffn2_gemm_db<<<dim3(DMODEL / 128, NTOK / 128), 256, 0, stream>>>(
          HbB, wdb, idx, cnt, out, dummy, e);
    }
  }
}

// Round 14
// 829.442 us; speedup vs baseline: 1.0519x; 1.0519x over previous
//
#include <hip/hip_runtime.h>
#include <hip/hip_bf16.h>
#include <math.h>

// Problem constants
#define NTOK   8192
#define DMODEL 2048
#define NEXP   8
#define RGATE  8
#define DFF    1024

#define NEG_SENTINEL (-3.0e38f)

using f32x4  = __attribute__((ext_vector_type(4))) float;
using short8 = __attribute__((ext_vector_type(8))) short;

// RNE float->bf16
static __device__ __forceinline__ short f2bf(float f) {
  union { float f; unsigned u; } v; v.f = f;
  unsigned r = v.u + 0x7fffu + ((v.u >> 16) & 1u);
  return (short)(r >> 16);
}
static __device__ __forceinline__ float bf2f(short s) {
  union { unsigned u; float f; } v; v.u = ((unsigned)(unsigned short)s) << 16;
  return v.f;
}
static __device__ __forceinline__ short8 cvt8(const float4 a, const float4 b) {
  short8 o;
  o[0] = f2bf(a.x); o[1] = f2bf(a.y); o[2] = f2bf(a.z); o[3] = f2bf(a.w);
  o[4] = f2bf(b.x); o[5] = f2bf(b.y); o[6] = f2bf(b.z); o[7] = f2bf(b.w);
  return o;
}

#define GLOAD_LDS(gp, lp)                                                  \
  __builtin_amdgcn_global_load_lds(                                        \
      (const __attribute__((address_space(1))) void*)(gp),                 \
      (__attribute__((address_space(3))) void*)(lp), 16, 0, 0)

// ---------------------------------------------------------------------------
// prep_all: ONE kernel for {zero cnt, cvt x->xb, cvt wd->wdb, pack wg/wu->wgu,
// optional out zero}.
// ---------------------------------------------------------------------------
#define SEG_CVT  2097152              // CNT/8 16B-chunk count
#define SEG_PACK 4194304              // NEXP*2048*(DMODEL/8)
__global__ __launch_bounds__(256) void prep_all(
    const float* __restrict__ x, const float* __restrict__ wd,
    const float* __restrict__ wg, const float* __restrict__ wu,
    short* __restrict__ xb, short* __restrict__ wdb, short* __restrict__ wgu,
    int* __restrict__ cnt, float4* __restrict__ out4, int zero_out) {
  if (blockIdx.x == 0 && threadIdx.x < 16) cnt[threadIdx.x] = 0;
  const int stride = gridDim.x * blockDim.x;
  const int total = SEG_CVT * 2 + SEG_PACK + (zero_out ? SEG_CVT : 0);
  for (int i = blockIdx.x * blockDim.x + threadIdx.x; i < total; i += stride) {
    if (i < SEG_CVT) {
      const float4 a = ((const float4*)x)[(size_t)i * 2];
      const float4 b = ((const float4*)x)[(size_t)i * 2 + 1];
      ((short8*)xb)[i] = cvt8(a, b);
    } else if (i < 2 * SEG_CVT) {
      const int j = i - SEG_CVT;
      const float4 a = ((const float4*)wd)[(size_t)j * 2];
      const float4 b = ((const float4*)wd)[(size_t)j * 2 + 1];
      ((short8*)wdb)[j] = cvt8(a, b);
    } else if (i < 2 * SEG_CVT + SEG_PACK) {
      const int j = i - 2 * SEG_CVT;
      const int c = j & 255;
      const int r = (j >> 8) & 2047;
      const int e = j >> 19;
      const int sel = (r >> 4) & 1;
      const int f = ((r >> 5) << 4) + (r & 15);
      const float* src = (sel ? wu : wg) + ((size_t)(e * DFF + f)) * DMODEL + c * 8;
      const float4 a = *(const float4*)src;
      const float4 b = *(const float4*)(src + 4);
      ((short8*)wgu)[j] = cvt8(a, b);
    } else {
      const int j = i - (2 * SEG_CVT + SEG_PACK);
      out4[(size_t)j * 2] = make_float4(0.f, 0.f, 0.f, 0.f);
      out4[(size_t)j * 2 + 1] = make_float4(0.f, 0.f, 0.f, 0.f);
    }
  }
}

// ---------------------------------------------------------------------------
// gate_v3: register outer-product gate + pos[e][n] inverse map (R10-proven).
// ---------------------------------------------------------------------------
__global__ __launch_bounds__(256) void gate_v3(
    const float* __restrict__ x, const float* __restrict__ W_A,
    const float* __restrict__ gscale, const float* __restrict__ gbias,
    float* __restrict__ gw, float* __restrict__ score_out,
    int* __restrict__ idx, int* __restrict__ pos, int* __restrict__ cnt) {
  __shared__ float ghs[32][65];
  const int tok0 = blockIdx.x * 32;
  const int t = threadIdx.x;
  const int ks = t & 3;
  const int posn = t >> 2;
  const int tg = posn & 7;
  const int rg = posn >> 3;
  const float* xp = x + (size_t)(tok0 + tg * 4) * DMODEL;
  const float* wp = W_A + (size_t)(rg * 8) * DMODEL;

  float acc[4][8];
#pragma unroll
  for (int i = 0; i < 4; ++i)
#pragma unroll
    for (int r = 0; r < 8; ++r) acc[i][r] = 0.f;

  float4 xa_[4], wa_[8], xb_[4], wb_[8];
  auto loadj = [&](int j, float4* xv, float4* wv) {
    const int k = ks * 4 + j * 16;
#pragma unroll
    for (int i = 0; i < 4; ++i) xv[i] = *(const float4*)(xp + (size_t)i * DMODEL + k);
#pragma unroll
    for (int r = 0; r < 8; ++r) wv[r] = *(const float4*)(wp + (size_t)r * DMODEL + k);
  };
  auto fmaj = [&](const float4* xv, const float4* wv) {
#pragma unroll
    for (int i = 0; i < 4; ++i)
#pragma unroll
      for (int r = 0; r < 8; ++r) {
        acc[i][r] = fmaf(xv[i].x, wv[r].x, acc[i][r]);
        acc[i][r] = fmaf(xv[i].y, wv[r].y, acc[i][r]);
        acc[i][r] = fmaf(xv[i].z, wv[r].z, acc[i][r]);
        acc[i][r] = fmaf(xv[i].w, wv[r].w, acc[i][r]);
      }
  };

  loadj(0, xa_, wa_);
#pragma unroll 1
  for (int j = 0; j < 128; j += 2) {
    loadj(j + 1, xb_, wb_);
    fmaj(xa_, wa_);
    if (j + 2 < 128) loadj(j + 2, xa_, wa_);
    fmaj(xb_, wb_);
  }

#pragma unroll
  for (int i = 0; i < 4; ++i)
#pragma unroll
    for (int r = 0; r < 8; ++r) {
      float v = acc[i][r];
      v += __shfl_xor(v, 1);
      v += __shfl_xor(v, 2);
      acc[i][r] = v;
    }
  if (ks == 0) {
#pragma unroll
    for (int i = 0; i < 4; ++i)
#pragma unroll
      for (int r = 0; r < 8; ++r) ghs[tg * 4 + i][rg * 8 + r] = acc[i][r];
  }
  __syncthreads();

  {
    const int tk = t >> 3, e = t & 7;
    const int n = tok0 + tk;
    float ss = 0.f;
#pragma unroll
    for (int r = 0; r < RGATE; ++r) { const float v = ghs[tk][e * 8 + r]; ss += v * v; }
    const float score = sqrtf(ss) * gscale[e] - gbias[e];
    const bool m = (score >= 0.0f);
    const float sig = 1.0f / (1.0f + expf(-score));
    gw[(size_t)n * NEXP + e] = m ? sig : 0.0f;
    score_out[(size_t)n * NEXP + e] = m ? score : NEG_SENTINEL;
    int slot = -1;
    if (m) {
      slot = atomicAdd(&cnt[e], 1);
      idx[(size_t)e * NTOK + slot] = n;
    }
    pos[(size_t)e * NTOK + n] = slot;
  }
}

// ===========================================================================
// Shared 256-tile compute macro (R12-proven quadrant phasing + setprio).
// ===========================================================================
#define CSWZ(ks_) ((((ks_) * 4 + (lane >> 4)) ^ (lane & 7)) << 4)

#define TILE256_COMPUTE(AS, BS)                                                \
  _Pragma("unroll") for (int ah_ = 0; ah_ < 2; ++ah_) {                        \
    short8 af_[4][2];                                                          \
    _Pragma("unroll") for (int q_ = 0; q_ < 4; ++q_)                           \
      _Pragma("unroll") for (int ks_ = 0; ks_ < 2; ++ks_)                      \
        af_[q_][ks_] = *(const short8*)((const char*)(AS) +                    \
            (arow + (ah_ * 4 + q_) * 16 + (lane & 15)) * 128 + CSWZ(ks_));     \
    _Pragma("unroll") for (int bh_ = 0; bh_ < 2; ++bh_) {                      \
      short8 bf_[2][2];                                                        \
      _Pragma("unroll") for (int q_ = 0; q_ < 2; ++q_)                         \
        _Pragma("unroll") for (int ks_ = 0; ks_ < 2; ++ks_)                    \
          bf_[q_][ks_] = *(const short8*)((const char*)(BS) +                  \
              (brow + (bh_ * 2 + q_) * 16 + (lane & 15)) * 128 + CSWZ(ks_));   \
      __builtin_amdgcn_s_setprio(1);                                           \
      _Pragma("unroll") for (int ks_ = 0; ks_ < 2; ++ks_)                      \
        _Pragma("unroll") for (int nf_ = 0; nf_ < 4; ++nf_)                    \
          _Pragma("unroll") for (int ff_ = 0; ff_ < 2; ++ff_)                  \
            acc[ah_ * 4 + nf_][bh_ * 2 + ff_] =                                \
                __builtin_amdgcn_mfma_f32_16x16x32_bf16(                       \
                    af_[nf_][ks_], bf_[ff_][ks_],                              \
                    acc[ah_ * 4 + nf_][bh_ * 2 + ff_], 0, 0, 0);               \
      __builtin_amdgcn_s_setprio(0);                                           \
    }                                                                          \
  }

// ===========================================================================
// ffn1_gemm256: REVERTED to R12 (proven 333 µs / MfmaUtil 32.5). R13's
// counted-vmcnt pipeline regressed (2 barriers/tile + sched_barrier pins
// defeat compiler scheduling — m141 failure mode) and is removed.
// ===========================================================================
#define FFN1_STAGE(AS, BS, k0)                                                 \
  _Pragma("unroll") for (int i_ = 0; i_ < 4; ++i_) {                           \
    const int row_ = wid * 32 + i_ * 8;                                        \
    GLOAD_LDS(xb + (size_t)tokA[i_] * DMODEL + (k0) + lk,                      \
              (char*)(AS) + row_ * 128);                                       \
    GLOAD_LDS(Bb + (size_t)(row_ + lr) * DMODEL + (k0) + lk,                   \
              (char*)(BS) + row_ * 128);                                       \
  }

__global__ __launch_bounds__(512, 2) void ffn1_gemm256(
    const short* __restrict__ xb, const short* __restrict__ wgu,
    const int* __restrict__ idx, const int* __restrict__ cnt,
    const float* __restrict__ gw, short* __restrict__ Hb, int e_arg) {
  const int e = (e_arg < 0) ? (int)blockIdx.z : e_arg;
  short* __restrict__ Hbe = Hb + ((e_arg < 0) ? (size_t)e * NTOK * DFF : (size_t)0);
  const int cnte = cnt[e];
  const int n0 = blockIdx.y * 256;
  if (n0 >= cnte) return;

  __shared__ __align__(16) short As0[256 * 64];
  __shared__ __align__(16) short Bs0[256 * 64];
  __shared__ __align__(16) short As1[256 * 64];
  __shared__ __align__(16) short Bs1[256 * 64];

  const int c0 = blockIdx.x * 256;
  const int t = threadIdx.x, lane = t & 63, wid = t >> 6;
  const int arow = (wid >> 2) * 128;
  const int brow = (wid & 3) * 64;
  const int* idxe = idx + (size_t)e * NTOK;
  const short* Bb = wgu + (size_t)e * 2048 * DMODEL + (size_t)c0 * DMODEL;
  const int lr = lane >> 3;
  const int lk = ((lane & 7) ^ lr) * 8;

  int tokA[4];
#pragma unroll
  for (int i = 0; i < 4; ++i) {
    int n = n0 + wid * 32 + i * 8 + lr;
    if (n >= cnte) n = cnte - 1;  // idx not pre-zeroed: clamp to valid slot
    tokA[i] = idxe[n];
  }

  f32x4 acc[8][4];
#pragma unroll
  for (int i = 0; i < 8; ++i)
#pragma unroll
    for (int j = 0; j < 4; ++j) acc[i][j] = (f32x4){0.f, 0.f, 0.f, 0.f};

  FFN1_STAGE(As0, Bs0, 0);
  __syncthreads();
#pragma unroll 1
  for (int kt = 0; kt < 32; kt += 2) {
    FFN1_STAGE(As1, Bs1, (kt + 1) * 64);
    TILE256_COMPUTE(As0, Bs0);
    __syncthreads();
    if (kt + 2 < 32) FFN1_STAGE(As0, Bs0, (kt + 2) * 64);
    TILE256_COMPUTE(As1, Bs1);
    __syncthreads();
  }

  const int fhalf = c0 >> 1;
#pragma unroll
  for (int nf = 0; nf < 8; ++nf) {
#pragma unroll
    for (int j = 0; j < 4; ++j) {
      const int n = n0 + arow + nf * 16 + (lane >> 4) * 4 + j;
      const bool valid = n < cnte;
      const int tok = valid ? idxe[n] : 0;
      const float gwv = gw[(size_t)tok * NEXP + e];
#pragma unroll
      for (int p = 0; p < 2; ++p) {
        const float gv = acc[nf][2 * p][j];
        const float uv = acc[nf][2 * p + 1][j];
        const float h = (gv / (1.f + expf(-gv))) * uv * gwv;
        const int f = fhalf + ((wid & 3) * 2 + p) * 16 + (lane & 15);
        Hbe[(size_t)n * DFF + f] = valid ? f2bf(h) : (short)0;
      }
    }
  }
}

// ===========================================================================
// ffn2z_gemm256: R14 change — ffn2 gets the R8/R12-proven 256² + dbuf +
// phasing treatment. A = compact Hb rows (linear, pad rows are exact zeros
// because ffn1's 256-row tiles write them), B = wdb, K = DFF = 1024.
// Writes bf16 partials into Cp slice (no out RMW).
// ===========================================================================
#define FFN2Z_STAGE(AS, BS, k0)                                                \
  _Pragma("unroll") for (int i_ = 0; i_ < 4; ++i_) {                           \
    const int row_ = wid * 32 + i_ * 8;                                        \
    GLOAD_LDS(Ab + (size_t)(row_ + lr) * DFF + (k0) + lk,                      \
              (char*)(AS) + row_ * 128);                                       \
    GLOAD_LDS(Bb + (size_t)(row_ + lr) * DFF + (k0) + lk,                      \
              (char*)(BS) + row_ * 128);                                       \
  }

__global__ __launch_bounds__(512, 2) void ffn2z_gemm256(
    const short* __restrict__ Hb, const short* __restrict__ wdb,
    const int* __restrict__ cnt, short* __restrict__ Cp, int e0) {
  const int e = e0 + blockIdx.z;
  const int cnte = cnt[e];
  const int n0 = blockIdx.y * 256;
  if (n0 >= cnte) return;

  __shared__ __align__(16) short As0[256 * 64];
  __shared__ __align__(16) short Bs0[256 * 64];
  __shared__ __align__(16) short As1[256 * 64];
  __shared__ __align__(16) short Bs1[256 * 64];

  const int c0 = blockIdx.x * 256;
  const int t = threadIdx.x, lane = t & 63, wid = t >> 6;
  const int arow = (wid >> 2) * 128;
  const int brow = (wid & 3) * 64;
  const short* Ab = Hb + (size_t)e * NTOK * DFF + (size_t)n0 * DFF;
  const short* Bb = wdb + (size_t)e * DMODEL * DFF + (size_t)c0 * DFF;
  short* Cpe = Cp + (size_t)blockIdx.z * NTOK * DMODEL;
  const int lr = lane >> 3;
  const int lk = ((lane & 7) ^ lr) * 8;

  f32x4 acc[8][4];
#pragma unroll
  for (int i = 0; i < 8; ++i)
#pragma unroll
    for (int j = 0; j < 4; ++j) acc[i][j] = (f32x4){0.f, 0.f, 0.f, 0.f};

  FFN2Z_STAGE(As0, Bs0, 0);
  __syncthreads();
#pragma unroll 1
  for (int kt = 0; kt < 16; kt += 2) {
    FFN2Z_STAGE(As1, Bs1, (kt + 1) * 64);
    TILE256_COMPUTE(As0, Bs0);
    __syncthreads();
    if (kt + 2 < 16) FFN2Z_STAGE(As0, Bs0, (kt + 2) * 64);
    TILE256_COMPUTE(As1, Bs1);
    __syncthreads();
  }

#pragma unroll
  for (int nf = 0; nf < 8; ++nf) {
#pragma unroll
    for (int j = 0; j < 4; ++j) {
      const int n = n0 + arow + nf * 16 + (lane >> 4) * 4 + j;
      if (n < cnte) {
#pragma unroll
        for (int c4 = 0; c4 < 4; ++c4) {
          const int d = c0 + brow + c4 * 16 + (lane & 15);
          Cpe[(size_t)n * DMODEL + d] = f2bf(acc[nf][c4][j]);
        }
      }
    }
  }
}

// ---------------------------------------------------------------------------
// reduce_out_g: out[n,:] (=|+=) sum_{e in group} Cp[z][pos[e][n],:] (R11).
// ---------------------------------------------------------------------------
__global__ __launch_bounds__(256) void reduce_out_g(
    const short* __restrict__ Cp, const int* __restrict__ pos,
    float* __restrict__ out, int e0, int ge, int accum) {
  const int n = blockIdx.x;
  const int t = threadIdx.x;
  float* op = out + (size_t)n * DMODEL + t * 8;
  float acc[8];
  if (accum) {
    const float4 a = *(const float4*)op;
    const float4 b = *(const float4*)(op + 4);
    acc[0] = a.x; acc[1] = a.y; acc[2] = a.z; acc[3] = a.w;
    acc[4] = b.x; acc[5] = b.y; acc[6] = b.z; acc[7] = b.w;
  } else {
#pragma unroll
    for (int j = 0; j < 8; ++j) acc[j] = 0.f;
  }
  for (int el = 0; el < ge; ++el) {
    const int p = pos[(size_t)(e0 + el) * NTOK + n];
    if (p >= 0) {
      const short8 v = *(const short8*)(Cp + (size_t)el * NTOK * DMODEL +
                                        (size_t)p * DMODEL + t * 8);
#pragma unroll
      for (int j = 0; j < 8; ++j) acc[j] += bf2f(v[j]);
    }
  }
  *(float4*)op = make_float4(acc[0], acc[1], acc[2], acc[3]);
  *(float4*)(op + 4) = make_float4(acc[4], acc[5], acc[6], acc[7]);
}

// ===========================================================================
// ffn2_gemm_db (fallback tiers only): R9-proven 128² out-RMW version.
// ===========================================================================
#define FFN2_STAGE(AS, BS, k0)                                                 \
  _Pragma("unroll") for (int i_ = 0; i_ < 4; ++i_) {                           \
    const int row_ = wid * 32 + i_ * 8;                                        \
    GLOAD_LDS(Ab + (size_t)(row_ + lr) * DFF + (k0) + lk,                      \
              (char*)(AS) + row_ * 128);                                       \
    GLOAD_LDS(Bb + (size_t)(row_ + lr) * DFF + (k0) + lk,                      \
              (char*)(BS) + row_ * 128);                                       \
  }

#define FFN2_COMPUTE(AS, BS)                                                   \
  {                                                                            \
    short8 af_[4][2];                                                          \
    _Pragma("unroll") for (int q_ = 0; q_ < 4; ++q_)                           \
      _Pragma("unroll") for (int ks_ = 0; ks_ < 2; ++ks_)                      \
        af_[q_][ks_] = *(const short8*)((const char*)(AS) +                    \
            (wr * 64 + q_ * 16 + (lane & 15)) * 128 + CSWZ(ks_));              \
    _Pragma("unroll") for (int bh_ = 0; bh_ < 2; ++bh_) {                      \
      short8 bf_[2][2];                                                        \
      _Pragma("unroll") for (int q_ = 0; q_ < 2; ++q_)                         \
        _Pragma("unroll") for (int ks_ = 0; ks_ < 2; ++ks_)                    \
          bf_[q_][ks_] = *(const short8*)((const char*)(BS) +                  \
              (wc * 64 + (bh_ * 2 + q_) * 16 + (lane & 15)) * 128 + CSWZ(ks_));\
      __builtin_amdgcn_s_setprio(1);                                           \
      _Pragma("unroll") for (int ks_ = 0; ks_ < 2; ++ks_)                      \
        _Pragma("unroll") for (int nf_ = 0; nf_ < 4; ++nf_)                    \
          _Pragma("unroll") for (int ff_ = 0; ff_ < 2; ++ff_)                  \
            acc[nf_][bh_ * 2 + ff_] =                                          \
                __builtin_amdgcn_mfma_f32_16x16x32_bf16(                       \
                    af_[nf_][ks_], bf_[ff_][ks_],                              \
                    acc[nf_][bh_ * 2 + ff_], 0, 0, 0);                         \
      __builtin_amdgcn_s_setprio(0);                                           \
    }                                                                          \
  }

__global__ __launch_bounds__(256, 2) void ffn2_gemm_db(
    const short* __restrict__ Hbe, const short* __restrict__ wdb,
    const int* __restrict__ idx, const int* __restrict__ cnt,
    float* __restrict__ out, float* __restrict__ dummy, int e) {
  const int cnte = cnt[e];
  const int n0 = blockIdx.y * 128;
  if (n0 >= cnte) return;
  __shared__ __align__(16) short As0[128 * 64];
  __shared__ __align__(16) short Bs0[128 * 64];
  __shared__ __align__(16) short As1[128 * 64];
  __shared__ __align__(16) short Bs1[128 * 64];

  const int c0 = blockIdx.x * 128;
  const int t = threadIdx.x, lane = t & 63, wid = t >> 6;
  const int wr = wid >> 1, wc = wid & 1;
  const int* idxe = idx + (size_t)e * NTOK;
  const short* Ab = Hbe + (size_t)n0 * DFF;
  const short* Bb = wdb + (size_t)e * DMODEL * DFF + (size_t)c0 * DFF;
  const int lr = lane >> 3;
  const int lk = ((lane & 7) ^ lr) * 8;

  f32x4 acc[4][4];
#pragma unroll
  for (int i = 0; i < 4; ++i)
#pragma unroll
    for (int j = 0; j < 4; ++j) acc[i][j] = (f32x4){0.f, 0.f, 0.f, 0.f};

  FFN2_STAGE(As0, Bs0, 0);
  __syncthreads();
#pragma unroll 1
  for (int kt = 0; kt < 16; kt += 2) {
    FFN2_STAGE(As1, Bs1, (kt + 1) * 64);
    FFN2_COMPUTE(As0, Bs0);
    __syncthreads();
    if (kt + 2 < 16) FFN2_STAGE(As0, Bs0, (kt + 2) * 64);
    FFN2_COMPUTE(As1, Bs1);
    __syncthreads();
  }

#pragma unroll
  for (int nf = 0; nf < 4; ++nf) {
#pragma unroll
    for (int j = 0; j < 4; ++j) {
      const int n = n0 + wr * 64 + nf * 16 + (lane >> 4) * 4 + j;
      const bool valid = n < cnte;
      const int tok = valid ? idxe[n] : 0;
      float* bp = valid ? (out + (size_t)tok * DMODEL) : dummy;
#pragma unroll
      for (int ff = 0; ff < 4; ++ff) {
        const int d = c0 + wc * 64 + ff * 16 + (lane & 15);
        bp[valid ? d : (d & 2047)] += acc[nf][ff][j];
      }
    }
  }
}

// ---------------------------------------------------------------------------
extern "C" void kernel_launch(void* const* d_in, const int* in_sizes, int n_in,
                              void* d_out, int out_size, void* d_ws, size_t ws_size,
                              hipStream_t stream) {
  const float* x      = (const float*)d_in[0];
  const float* W_A    = (const float*)d_in[1];
  const float* gscale = (const float*)d_in[2];
  const float* gbias  = (const float*)d_in[3];
  const float* wg     = (const float*)d_in[4];
  const float* wu     = (const float*)d_in[5];
  const float* wd     = (const float*)d_in[6];

  float* out       = (float*)d_out;                // [N, D]
  float* score_out = out + (size_t)NTOK * DMODEL;  // [N, E]

  // ws layout: gw | idx | pos | cnt | dummy | wdb | Hb(8x) | xb | wgu
  // Tier-C-grouped: Cp (G x 32MB slices) aliases xb+wgu (dead after ffn1).
  const size_t CNT = (size_t)16777216;
  const size_t CP_SLICE = (size_t)NTOK * DMODEL * 2;  // 32 MB
  size_t off = 0;
  float* gw    = (float*)((char*)d_ws + off); off += (size_t)NTOK * NEXP * 4;
  int*   idx   = (int*)((char*)d_ws + off);   off += (size_t)NEXP * NTOK * 4;
  int*   pos   = (int*)((char*)d_ws + off);   off += (size_t)NEXP * NTOK * 4;
  int*   cnt   = (int*)((char*)d_ws + off);   off += 16 * 4;
  float* dummy = (float*)((char*)d_ws + off); off += (size_t)DMODEL * 4;
  short* wdb   = (short*)((char*)d_ws + off); off += CNT * 2;
  const size_t hb_off = off;
  short* Hb    = (short*)((char*)d_ws + off); off += (size_t)NEXP * NTOK * DFF * 2;
  const size_t xb_off = off;
  short* xb    = (short*)((char*)d_ws + off); off += CNT * 2;
  short* wgu   = (short*)((char*)d_ws + off); off += CNT * 4;
  const size_t needA = off;
  short* Cp    = (short*)((char*)d_ws + xb_off);

  const bool tierA = (ws_size >= needA);
  int G = 0;
  if (tierA) {
    size_t avail = ws_size - xb_off;
    G = (int)(avail / CP_SLICE);
    if (G > NEXP) G = NEXP;
  }

  // Tier B layout (shared Hb)
  short* HbB  = Hb;
  short* xbB  = (short*)((char*)d_ws + hb_off + (size_t)NTOK * DFF * 2);
  short* wguB = xbB + CNT;

  const int zero_out = (tierA && G >= 1) ? 0 : 1;
  short* xbT  = tierA ? xb : xbB;
  short* wguT = tierA ? wgu : wguB;

  prep_all<<<2048, 256, 0, stream>>>(x, wd, wg, wu, xbT, wdb, wguT, cnt,
                                     (float4*)out, zero_out);
  gate_v3<<<NTOK / 32, 256, 0, stream>>>(x, W_A, gscale, gbias, gw,
                                         score_out, idx, pos, cnt);

  if (tierA && G >= 1) {
    ffn1_gemm256<<<dim3(2048 / 256, NTOK / 256, NEXP), 512, 0, stream>>>(
        xb, wgu, idx, cnt, gw, Hb, -1);
    const int np = (NEXP + G - 1) / G;
    int e0 = 0;
    for (int p = 0; p < np; ++p) {
      const int rem_p = np - p;
      const int ge = (NEXP - e0 + rem_p - 1) / rem_p;
      ffn2z_gemm256<<<dim3(DMODEL / 256, NTOK / 256, ge), 512, 0, stream>>>(
          Hb, wdb, cnt, Cp, e0);
      reduce_out_g<<<NTOK, 256, 0, stream>>>(Cp, pos, out, e0, ge, p > 0);
      e0 += ge;
    }
  } else if (tierA) {
    ffn1_gemm256<<<dim3(2048 / 256, NTOK / 256, NEXP), 512, 0, stream>>>(
        xb, wgu, idx, cnt, gw, Hb, -1);
    for (int e = 0; e < NEXP; ++e)
      ffn2_gemm_db<<<dim3(DMODEL / 128, NTOK / 128), 256, 0, stream>>>(
          Hb + (size_t)e * NTOK * DFF, wdb, idx, cnt, out, dummy, e);
  } else {
    for (int e = 0; e < NEXP; ++e) {
      ffn1_gemm256<<<dim3(2048 / 256, NTOK / 256), 512, 0, stream>>>(
          xbB, wguB, idx, cnt, gw, HbB, e);
      ffn2_gemm_db<<<dim3(DMODEL / 128, NTOK / 128), 256, 0, stream>>>(
          HbB, wdb, idx, cnt, out, dummy, e);
    }
  }
}

// Round 15
// 811.074 us; speedup vs baseline: 1.0757x; 1.0226x over previous
//
#include <hip/hip_runtime.h>
#include <hip/hip_bf16.h>
#include <math.h>

// Problem constants
#define NTOK   8192
#define DMODEL 2048
#define NEXP   8
#define RGATE  8
#define DFF    1024

#define NEG_SENTINEL (-3.0e38f)

using f32x4  = __attribute__((ext_vector_type(4))) float;
using short8 = __attribute__((ext_vector_type(8))) short;

// RNE float->bf16
static __device__ __forceinline__ short f2bf(float f) {
  union { float f; unsigned u; } v; v.f = f;
  unsigned r = v.u + 0x7fffu + ((v.u >> 16) & 1u);
  return (short)(r >> 16);
}
static __device__ __forceinline__ float bf2f(short s) {
  union { unsigned u; float f; } v; v.u = ((unsigned)(unsigned short)s) << 16;
  return v.f;
}
static __device__ __forceinline__ short8 cvt8(const float4 a, const float4 b) {
  short8 o;
  o[0] = f2bf(a.x); o[1] = f2bf(a.y); o[2] = f2bf(a.z); o[3] = f2bf(a.w);
  o[4] = f2bf(b.x); o[5] = f2bf(b.y); o[6] = f2bf(b.z); o[7] = f2bf(b.w);
  return o;
}

#define GLOAD_LDS(gp, lp)                                                  \
  __builtin_amdgcn_global_load_lds(                                        \
      (const __attribute__((address_space(1))) void*)(gp),                 \
      (__attribute__((address_space(3))) void*)(lp), 16, 0, 0)

// T1 XCD swizzle (per z-slice of 256 blocks; 256%8==0 keeps XCD == d'%8):
// groups the 8 x-blocks sharing one A-panel (same y,z) onto ONE XCD,
// adjacent in dispatch order, so the panel is fetched once into that L2.
// Bijective: d' = c + 8*(yi*8 + x), decode x = g&7, y = yi*8 + c.
static __device__ __forceinline__ void xcd_swz(int bx, int by, int& sx, int& sy) {
  const int dl = bx + by * 8;        // 0..255
  const int c  = dl & 7;             // XCD lane
  const int g  = dl >> 3;            // 0..31
  sx = g & 7;
  sy = ((g >> 3) << 3) + c;
}

// ---------------------------------------------------------------------------
// prep_all: ONE kernel for {zero cnt, cvt x->xb, cvt wd->wdb, pack wg/wu->wgu,
// optional out zero}.
// ---------------------------------------------------------------------------
#define SEG_CVT  2097152              // CNT/8 16B-chunk count
#define SEG_PACK 4194304              // NEXP*2048*(DMODEL/8)
__global__ __launch_bounds__(256) void prep_all(
    const float* __restrict__ x, const float* __restrict__ wd,
    const float* __restrict__ wg, const float* __restrict__ wu,
    short* __restrict__ xb, short* __restrict__ wdb, short* __restrict__ wgu,
    int* __restrict__ cnt, float4* __restrict__ out4, int zero_out) {
  if (blockIdx.x == 0 && threadIdx.x < 16) cnt[threadIdx.x] = 0;
  const int stride = gridDim.x * blockDim.x;
  const int total = SEG_CVT * 2 + SEG_PACK + (zero_out ? SEG_CVT : 0);
  for (int i = blockIdx.x * blockDim.x + threadIdx.x; i < total; i += stride) {
    if (i < SEG_CVT) {
      const float4 a = ((const float4*)x)[(size_t)i * 2];
      const float4 b = ((const float4*)x)[(size_t)i * 2 + 1];
      ((short8*)xb)[i] = cvt8(a, b);
    } else if (i < 2 * SEG_CVT) {
      const int j = i - SEG_CVT;
      const float4 a = ((const float4*)wd)[(size_t)j * 2];
      const float4 b = ((const float4*)wd)[(size_t)j * 2 + 1];
      ((short8*)wdb)[j] = cvt8(a, b);
    } else if (i < 2 * SEG_CVT + SEG_PACK) {
      const int j = i - 2 * SEG_CVT;
      const int c = j & 255;
      const int r = (j >> 8) & 2047;
      const int e = j >> 19;
      const int sel = (r >> 4) & 1;
      const int f = ((r >> 5) << 4) + (r & 15);
      const float* src = (sel ? wu : wg) + ((size_t)(e * DFF + f)) * DMODEL + c * 8;
      const float4 a = *(const float4*)src;
      const float4 b = *(const float4*)(src + 4);
      ((short8*)wgu)[j] = cvt8(a, b);
    } else {
      const int j = i - (2 * SEG_CVT + SEG_PACK);
      out4[(size_t)j * 2] = make_float4(0.f, 0.f, 0.f, 0.f);
      out4[(size_t)j * 2 + 1] = make_float4(0.f, 0.f, 0.f, 0.f);
    }
  }
}

// ---------------------------------------------------------------------------
// gate_v3: register outer-product gate + pos[e][n] inverse map (R10-proven).
// ---------------------------------------------------------------------------
__global__ __launch_bounds__(256) void gate_v3(
    const float* __restrict__ x, const float* __restrict__ W_A,
    const float* __restrict__ gscale, const float* __restrict__ gbias,
    float* __restrict__ gw, float* __restrict__ score_out,
    int* __restrict__ idx, int* __restrict__ pos, int* __restrict__ cnt) {
  __shared__ float ghs[32][65];
  const int tok0 = blockIdx.x * 32;
  const int t = threadIdx.x;
  const int ks = t & 3;
  const int posn = t >> 2;
  const int tg = posn & 7;
  const int rg = posn >> 3;
  const float* xp = x + (size_t)(tok0 + tg * 4) * DMODEL;
  const float* wp = W_A + (size_t)(rg * 8) * DMODEL;

  float acc[4][8];
#pragma unroll
  for (int i = 0; i < 4; ++i)
#pragma unroll
    for (int r = 0; r < 8; ++r) acc[i][r] = 0.f;

  float4 xa_[4], wa_[8], xb_[4], wb_[8];
  auto loadj = [&](int j, float4* xv, float4* wv) {
    const int k = ks * 4 + j * 16;
#pragma unroll
    for (int i = 0; i < 4; ++i) xv[i] = *(const float4*)(xp + (size_t)i * DMODEL + k);
#pragma unroll
    for (int r = 0; r < 8; ++r) wv[r] = *(const float4*)(wp + (size_t)r * DMODEL + k);
  };
  auto fmaj = [&](const float4* xv, const float4* wv) {
#pragma unroll
    for (int i = 0; i < 4; ++i)
#pragma unroll
      for (int r = 0; r < 8; ++r) {
        acc[i][r] = fmaf(xv[i].x, wv[r].x, acc[i][r]);
        acc[i][r] = fmaf(xv[i].y, wv[r].y, acc[i][r]);
        acc[i][r] = fmaf(xv[i].z, wv[r].z, acc[i][r]);
        acc[i][r] = fmaf(xv[i].w, wv[r].w, acc[i][r]);
      }
  };

  loadj(0, xa_, wa_);
#pragma unroll 1
  for (int j = 0; j < 128; j += 2) {
    loadj(j + 1, xb_, wb_);
    fmaj(xa_, wa_);
    if (j + 2 < 128) loadj(j + 2, xa_, wa_);
    fmaj(xb_, wb_);
  }

#pragma unroll
  for (int i = 0; i < 4; ++i)
#pragma unroll
    for (int r = 0; r < 8; ++r) {
      float v = acc[i][r];
      v += __shfl_xor(v, 1);
      v += __shfl_xor(v, 2);
      acc[i][r] = v;
    }
  if (ks == 0) {
#pragma unroll
    for (int i = 0; i < 4; ++i)
#pragma unroll
      for (int r = 0; r < 8; ++r) ghs[tg * 4 + i][rg * 8 + r] = acc[i][r];
  }
  __syncthreads();

  {
    const int tk = t >> 3, e = t & 7;
    const int n = tok0 + tk;
    float ss = 0.f;
#pragma unroll
    for (int r = 0; r < RGATE; ++r) { const float v = ghs[tk][e * 8 + r]; ss += v * v; }
    const float score = sqrtf(ss) * gscale[e] - gbias[e];
    const bool m = (score >= 0.0f);
    const float sig = 1.0f / (1.0f + expf(-score));
    gw[(size_t)n * NEXP + e] = m ? sig : 0.0f;
    score_out[(size_t)n * NEXP + e] = m ? score : NEG_SENTINEL;
    int slot = -1;
    if (m) {
      slot = atomicAdd(&cnt[e], 1);
      idx[(size_t)e * NTOK + slot] = n;
    }
    pos[(size_t)e * NTOK + n] = slot;
  }
}

// ===========================================================================
// Shared 256-tile compute macro (R12-proven quadrant phasing + setprio).
// ===========================================================================
#define CSWZ(ks_) ((((ks_) * 4 + (lane >> 4)) ^ (lane & 7)) << 4)

#define TILE256_COMPUTE(AS, BS)                                                \
  _Pragma("unroll") for (int ah_ = 0; ah_ < 2; ++ah_) {                        \
    short8 af_[4][2];                                                          \
    _Pragma("unroll") for (int q_ = 0; q_ < 4; ++q_)                           \
      _Pragma("unroll") for (int ks_ = 0; ks_ < 2; ++ks_)                      \
        af_[q_][ks_] = *(const short8*)((const char*)(AS) +                    \
            (arow + (ah_ * 4 + q_) * 16 + (lane & 15)) * 128 + CSWZ(ks_));     \
    _Pragma("unroll") for (int bh_ = 0; bh_ < 2; ++bh_) {                      \
      short8 bf_[2][2];                                                        \
      _Pragma("unroll") for (int q_ = 0; q_ < 2; ++q_)                         \
        _Pragma("unroll") for (int ks_ = 0; ks_ < 2; ++ks_)                    \
          bf_[q_][ks_] = *(const short8*)((const char*)(BS) +                  \
              (brow + (bh_ * 2 + q_) * 16 + (lane & 15)) * 128 + CSWZ(ks_));   \
      __builtin_amdgcn_s_setprio(1);                                           \
      _Pragma("unroll") for (int ks_ = 0; ks_ < 2; ++ks_)                      \
        _Pragma("unroll") for (int nf_ = 0; nf_ < 4; ++nf_)                    \
          _Pragma("unroll") for (int ff_ = 0; ff_ < 2; ++ff_)                  \
            acc[ah_ * 4 + nf_][bh_ * 2 + ff_] =                                \
                __builtin_amdgcn_mfma_f32_16x16x32_bf16(                       \
                    af_[nf_][ks_], bf_[ff_][ks_],                              \
                    acc[ah_ * 4 + nf_][bh_ * 2 + ff_], 0, 0, 0);               \
      __builtin_amdgcn_s_setprio(0);                                           \
    }                                                                          \
  }

// ===========================================================================
// ffn1_gemm256: R12 structure (proven 333 µs) + R15 T1 XCD swizzle.
// ===========================================================================
#define FFN1_STAGE(AS, BS, k0)                                                 \
  _Pragma("unroll") for (int i_ = 0; i_ < 4; ++i_) {                           \
    const int row_ = wid * 32 + i_ * 8;                                        \
    GLOAD_LDS(xb + (size_t)tokA[i_] * DMODEL + (k0) + lk,                      \
              (char*)(AS) + row_ * 128);                                       \
    GLOAD_LDS(Bb + (size_t)(row_ + lr) * DMODEL + (k0) + lk,                   \
              (char*)(BS) + row_ * 128);                                       \
  }

__global__ __launch_bounds__(512, 2) void ffn1_gemm256(
    const short* __restrict__ xb, const short* __restrict__ wgu,
    const int* __restrict__ idx, const int* __restrict__ cnt,
    const float* __restrict__ gw, short* __restrict__ Hb, int e_arg) {
  int sx, sy, e;
  if (e_arg < 0) {
    xcd_swz(blockIdx.x, blockIdx.y, sx, sy);
    e = blockIdx.z;
  } else {
    sx = blockIdx.x; sy = blockIdx.y; e = e_arg;
  }
  short* __restrict__ Hbe = Hb + ((e_arg < 0) ? (size_t)e * NTOK * DFF : (size_t)0);
  const int cnte = cnt[e];
  const int n0 = sy * 256;
  if (n0 >= cnte) return;

  __shared__ __align__(16) short As0[256 * 64];
  __shared__ __align__(16) short Bs0[256 * 64];
  __shared__ __align__(16) short As1[256 * 64];
  __shared__ __align__(16) short Bs1[256 * 64];

  const int c0 = sx * 256;
  const int t = threadIdx.x, lane = t & 63, wid = t >> 6;
  const int arow = (wid >> 2) * 128;
  const int brow = (wid & 3) * 64;
  const int* idxe = idx + (size_t)e * NTOK;
  const short* Bb = wgu + (size_t)e * 2048 * DMODEL + (size_t)c0 * DMODEL;
  const int lr = lane >> 3;
  const int lk = ((lane & 7) ^ lr) * 8;

  int tokA[4];
#pragma unroll
  for (int i = 0; i < 4; ++i) {
    int n = n0 + wid * 32 + i * 8 + lr;
    if (n >= cnte) n = cnte - 1;  // idx not pre-zeroed: clamp to valid slot
    tokA[i] = idxe[n];
  }

  f32x4 acc[8][4];
#pragma unroll
  for (int i = 0; i < 8; ++i)
#pragma unroll
    for (int j = 0; j < 4; ++j) acc[i][j] = (f32x4){0.f, 0.f, 0.f, 0.f};

  FFN1_STAGE(As0, Bs0, 0);
  __syncthreads();
#pragma unroll 1
  for (int kt = 0; kt < 32; kt += 2) {
    FFN1_STAGE(As1, Bs1, (kt + 1) * 64);
    TILE256_COMPUTE(As0, Bs0);
    __syncthreads();
    if (kt + 2 < 32) FFN1_STAGE(As0, Bs0, (kt + 2) * 64);
    TILE256_COMPUTE(As1, Bs1);
    __syncthreads();
  }

  const int fhalf = c0 >> 1;
#pragma unroll
  for (int nf = 0; nf < 8; ++nf) {
#pragma unroll
    for (int j = 0; j < 4; ++j) {
      const int n = n0 + arow + nf * 16 + (lane >> 4) * 4 + j;
      const bool valid = n < cnte;
      const int tok = valid ? idxe[n] : 0;
      const float gwv = gw[(size_t)tok * NEXP + e];
#pragma unroll
      for (int p = 0; p < 2; ++p) {
        const float gv = acc[nf][2 * p][j];
        const float uv = acc[nf][2 * p + 1][j];
        const float h = (gv / (1.f + expf(-gv))) * uv * gwv;
        const int f = fhalf + ((wid & 3) * 2 + p) * 16 + (lane & 15);
        Hbe[(size_t)n * DFF + f] = valid ? f2bf(h) : (short)0;
      }
    }
  }
}

// ===========================================================================
// ffn2z_gemm256: R14 structure + R15 T1 XCD swizzle. Partials into Cp.
// ===========================================================================
#define FFN2Z_STAGE(AS, BS, k0)                                                \
  _Pragma("unroll") for (int i_ = 0; i_ < 4; ++i_) {                           \
    const int row_ = wid * 32 + i_ * 8;                                        \
    GLOAD_LDS(Ab + (size_t)(row_ + lr) * DFF + (k0) + lk,                      \
              (char*)(AS) + row_ * 128);                                       \
    GLOAD_LDS(Bb + (size_t)(row_ + lr) * DFF + (k0) + lk,                      \
              (char*)(BS) + row_ * 128);                                       \
  }

__global__ __launch_bounds__(512, 2) void ffn2z_gemm256(
    const short* __restrict__ Hb, const short* __restrict__ wdb,
    const int* __restrict__ cnt, short* __restrict__ Cp, int e0) {
  int sx, sy;
  xcd_swz(blockIdx.x, blockIdx.y, sx, sy);
  const int e = e0 + blockIdx.z;
  const int cnte = cnt[e];
  const int n0 = sy * 256;
  if (n0 >= cnte) return;

  __shared__ __align__(16) short As0[256 * 64];
  __shared__ __align__(16) short Bs0[256 * 64];
  __shared__ __align__(16) short As1[256 * 64];
  __shared__ __align__(16) short Bs1[256 * 64];

  const int c0 = sx * 256;
  const int t = threadIdx.x, lane = t & 63, wid = t >> 6;
  const int arow = (wid >> 2) * 128;
  const int brow = (wid & 3) * 64;
  const short* Ab = Hb + (size_t)e * NTOK * DFF + (size_t)n0 * DFF;
  const short* Bb = wdb + (size_t)e * DMODEL * DFF + (size_t)c0 * DFF;
  short* Cpe = Cp + (size_t)blockIdx.z * NTOK * DMODEL;
  const int lr = lane >> 3;
  const int lk = ((lane & 7) ^ lr) * 8;

  f32x4 acc[8][4];
#pragma unroll
  for (int i = 0; i < 8; ++i)
#pragma unroll
    for (int j = 0; j < 4; ++j) acc[i][j] = (f32x4){0.f, 0.f, 0.f, 0.f};

  FFN2Z_STAGE(As0, Bs0, 0);
  __syncthreads();
#pragma unroll 1
  for (int kt = 0; kt < 16; kt += 2) {
    FFN2Z_STAGE(As1, Bs1, (kt + 1) * 64);
    TILE256_COMPUTE(As0, Bs0);
    __syncthreads();
    if (kt + 2 < 16) FFN2Z_STAGE(As0, Bs0, (kt + 2) * 64);
    TILE256_COMPUTE(As1, Bs1);
    __syncthreads();
  }

#pragma unroll
  for (int nf = 0; nf < 8; ++nf) {
#pragma unroll
    for (int j = 0; j < 4; ++j) {
      const int n = n0 + arow + nf * 16 + (lane >> 4) * 4 + j;
      if (n < cnte) {
#pragma unroll
        for (int c4 = 0; c4 < 4; ++c4) {
          const int d = c0 + brow + c4 * 16 + (lane & 15);
          Cpe[(size_t)n * DMODEL + d] = f2bf(acc[nf][c4][j]);
        }
      }
    }
  }
}

// ---------------------------------------------------------------------------
// reduce_out_g: out[n,:] (=|+=) sum_{e in group} Cp[z][pos[e][n],:] (R11).
// ---------------------------------------------------------------------------
__global__ __launch_bounds__(256) void reduce_out_g(
    const short* __restrict__ Cp, const int* __restrict__ pos,
    float* __restrict__ out, int e0, int ge, int accum) {
  const int n = blockIdx.x;
  const int t = threadIdx.x;
  float* op = out + (size_t)n * DMODEL + t * 8;
  float acc[8];
  if (accum) {
    const float4 a = *(const float4*)op;
    const float4 b = *(const float4*)(op + 4);
    acc[0] = a.x; acc[1] = a.y; acc[2] = a.z; acc[3] = a.w;
    acc[4] = b.x; acc[5] = b.y; acc[6] = b.z; acc[7] = b.w;
  } else {
#pragma unroll
    for (int j = 0; j < 8; ++j) acc[j] = 0.f;
  }
  for (int el = 0; el < ge; ++el) {
    const int p = pos[(size_t)(e0 + el) * NTOK + n];
    if (p >= 0) {
      const short8 v = *(const short8*)(Cp + (size_t)el * NTOK * DMODEL +
                                        (size_t)p * DMODEL + t * 8);
#pragma unroll
      for (int j = 0; j < 8; ++j) acc[j] += bf2f(v[j]);
    }
  }
  *(float4*)op = make_float4(acc[0], acc[1], acc[2], acc[3]);
  *(float4*)(op + 4) = make_float4(acc[4], acc[5], acc[6], acc[7]);
}

// ===========================================================================
// ffn2_gemm_db (fallback tiers only): R9-proven 128² out-RMW version.
// ===========================================================================
#define FFN2_STAGE(AS, BS, k0)                                                 \
  _Pragma("unroll") for (int i_ = 0; i_ < 4; ++i_) {                           \
    const int row_ = wid * 32 + i_ * 8;                                        \
    GLOAD_LDS(Ab + (size_t)(row_ + lr) * DFF + (k0) + lk,                      \
              (char*)(AS) + row_ * 128);                                       \
    GLOAD_LDS(Bb + (size_t)(row_ + lr) * DFF + (k0) + lk,                      \
              (char*)(BS) + row_ * 128);                                       \
  }

#define FFN2_COMPUTE(AS, BS)                                                   \
  {                                                                            \
    short8 af_[4][2];                                                          \
    _Pragma("unroll") for (int q_ = 0; q_ < 4; ++q_)                           \
      _Pragma("unroll") for (int ks_ = 0; ks_ < 2; ++ks_)                      \
        af_[q_][ks_] = *(const short8*)((const char*)(AS) +                    \
            (wr * 64 + q_ * 16 + (lane & 15)) * 128 + CSWZ(ks_));              \
    _Pragma("unroll") for (int bh_ = 0; bh_ < 2; ++bh_) {                      \
      short8 bf_[2][2];                                                        \
      _Pragma("unroll") for (int q_ = 0; q_ < 2; ++q_)                         \
        _Pragma("unroll") for (int ks_ = 0; ks_ < 2; ++ks_)                    \
          bf_[q_][ks_] = *(const short8*)((const char*)(BS) +                  \
              (wc * 64 + (bh_ * 2 + q_) * 16 + (lane & 15)) * 128 + CSWZ(ks_));\
      __builtin_amdgcn_s_setprio(1);                                           \
      _Pragma("unroll") for (int ks_ = 0; ks_ < 2; ++ks_)                      \
        _Pragma("unroll") for (int nf_ = 0; nf_ < 4; ++nf_)                    \
          _Pragma("unroll") for (int ff_ = 0; ff_ < 2; ++ff_)                  \
            acc[nf_][bh_ * 2 + ff_] =                                          \
                __builtin_amdgcn_mfma_f32_16x16x32_bf16(                       \
                    af_[nf_][ks_], bf_[ff_][ks_],                              \
                    acc[nf_][bh_ * 2 + ff_], 0, 0, 0);                         \
      __builtin_amdgcn_s_setprio(0);                                           \
    }                                                                          \
  }

__global__ __launch_bounds__(256, 2) void ffn2_gemm_db(
    const short* __restrict__ Hbe, const short* __restrict__ wdb,
    const int* __restrict__ idx, const int* __restrict__ cnt,
    float* __restrict__ out, float* __restrict__ dummy, int e) {
  const int cnte = cnt[e];
  const int n0 = blockIdx.y * 128;
  if (n0 >= cnte) return;
  __shared__ __align__(16) short As0[128 * 64];
  __shared__ __align__(16) short Bs0[128 * 64];
  __shared__ __align__(16) short As1[128 * 64];
  __shared__ __align__(16) short Bs1[128 * 64];

  const int c0 = blockIdx.x * 128;
  const int t = threadIdx.x, lane = t & 63, wid = t >> 6;
  const int wr = wid >> 1, wc = wid & 1;
  const int* idxe = idx + (size_t)e * NTOK;
  const short* Ab = Hbe + (size_t)n0 * DFF;
  const short* Bb = wdb + (size_t)e * DMODEL * DFF + (size_t)c0 * DFF;
  const int lr = lane >> 3;
  const int lk = ((lane & 7) ^ lr) * 8;

  f32x4 acc[4][4];
#pragma unroll
  for (int i = 0; i < 4; ++i)
#pragma unroll
    for (int j = 0; j < 4; ++j) acc[i][j] = (f32x4){0.f, 0.f, 0.f, 0.f};

  FFN2_STAGE(As0, Bs0, 0);
  __syncthreads();
#pragma unroll 1
  for (int kt = 0; kt < 16; kt += 2) {
    FFN2_STAGE(As1, Bs1, (kt + 1) * 64);
    FFN2_COMPUTE(As0, Bs0);
    __syncthreads();
    if (kt + 2 < 16) FFN2_STAGE(As0, Bs0, (kt + 2) * 64);
    FFN2_COMPUTE(As1, Bs1);
    __syncthreads();
  }

#pragma unroll
  for (int nf = 0; nf < 4; ++nf) {
#pragma unroll
    for (int j = 0; j < 4; ++j) {
      const int n = n0 + wr * 64 + nf * 16 + (lane >> 4) * 4 + j;
      const bool valid = n < cnte;
      const int tok = valid ? idxe[n] : 0;
      float* bp = valid ? (out + (size_t)tok * DMODEL) : dummy;
#pragma unroll
      for (int ff = 0; ff < 4; ++ff) {
        const int d = c0 + wc * 64 + ff * 16 + (lane & 15);
        bp[valid ? d : (d & 2047)] += acc[nf][ff][j];
      }
    }
  }
}

// ---------------------------------------------------------------------------
extern "C" void kernel_launch(void* const* d_in, const int* in_sizes, int n_in,
                              void* d_out, int out_size, void* d_ws, size_t ws_size,
                              hipStream_t stream) {
  const float* x      = (const float*)d_in[0];
  const float* W_A    = (const float*)d_in[1];
  const float* gscale = (const float*)d_in[2];
  const float* gbias  = (const float*)d_in[3];
  const float* wg     = (const float*)d_in[4];
  const float* wu     = (const float*)d_in[5];
  const float* wd     = (const float*)d_in[6];

  float* out       = (float*)d_out;                // [N, D]
  float* score_out = out + (size_t)NTOK * DMODEL;  // [N, E]

  // ws layout: gw | idx | pos | cnt | dummy | wdb | Hb(8x) | xb | wgu
  // Tier-C-grouped: Cp (G x 32MB slices) aliases xb+wgu (dead after ffn1).
  const size_t CNT = (size_t)16777216;
  const size_t CP_SLICE = (size_t)NTOK * DMODEL * 2;  // 32 MB
  size_t off = 0;
  float* gw    = (float*)((char*)d_ws + off); off += (size_t)NTOK * NEXP * 4;
  int*   idx   = (int*)((char*)d_ws + off);   off += (size_t)NEXP * NTOK * 4;
  int*   pos   = (int*)((char*)d_ws + off);   off += (size_t)NEXP * NTOK * 4;
  int*   cnt   = (int*)((char*)d_ws + off);   off += 16 * 4;
  float* dummy = (float*)((char*)d_ws + off); off += (size_t)DMODEL * 4;
  short* wdb   = (short*)((char*)d_ws + off); off += CNT * 2;
  const size_t hb_off = off;
  short* Hb    = (short*)((char*)d_ws + off); off += (size_t)NEXP * NTOK * DFF * 2;
  const size_t xb_off = off;
  short* xb    = (short*)((char*)d_ws + off); off += CNT * 2;
  short* wgu   = (short*)((char*)d_ws + off); off += CNT * 4;
  const size_t needA = off;
  short* Cp    = (short*)((char*)d_ws + xb_off);

  const bool tierA = (ws_size >= needA);
  int G = 0;
  if (tierA) {
    size_t avail = ws_size - xb_off;
    G = (int)(avail / CP_SLICE);
    if (G > NEXP) G = NEXP;
  }

  // Tier B layout (shared Hb)
  short* HbB  = Hb;
  short* xbB  = (short*)((char*)d_ws + hb_off + (size_t)NTOK * DFF * 2);
  short* wguB = xbB + CNT;

  const int zero_out = (tierA && G >= 1) ? 0 : 1;
  short* xbT  = tierA ? xb : xbB;
  short* wguT = tierA ? wgu : wguB;

  prep_all<<<2048, 256, 0, stream>>>(x, wd, wg, wu, xbT, wdb, wguT, cnt,
                                     (float4*)out, zero_out);
  gate_v3<<<NTOK / 32, 256, 0, stream>>>(x, W_A, gscale, gbias, gw,
                                         score_out, idx, pos, cnt);

  if (tierA && G >= 1) {
    ffn1_gemm256<<<dim3(2048 / 256, NTOK / 256, NEXP), 512, 0, stream>>>(
        xb, wgu, idx, cnt, gw, Hb, -1);
    const int np = (NEXP + G - 1) / G;
    int e0 = 0;
    for (int p = 0; p < np; ++p) {
      const int rem_p = np - p;
      const int ge = (NEXP - e0 + rem_p - 1) / rem_p;
      ffn2z_gemm256<<<dim3(DMODEL / 256, NTOK / 256, ge), 512, 0, stream>>>(
          Hb, wdb, cnt, Cp, e0);
      reduce_out_g<<<NTOK, 256, 0, stream>>>(Cp, pos, out, e0, ge, p > 0);
      e0 += ge;
    }
  } else if (tierA) {
    ffn1_gemm256<<<dim3(2048 / 256, NTOK / 256, NEXP), 512, 0, stream>>>(
        xb, wgu, idx, cnt, gw, Hb, -1);
    for (int e = 0; e < NEXP; ++e)
      ffn2_gemm_db<<<dim3(DMODEL / 128, NTOK / 128), 256, 0, stream>>>(
          Hb + (size_t)e * NTOK * DFF, wdb, idx, cnt, out, dummy, e);
  } else {
    for (int e = 0; e < NEXP; ++e) {
      ffn1_gemm256<<<dim3(2048 / 256, NTOK / 256), 512, 0, stream>>>(
          xbB, wguB, idx, cnt, gw, HbB, e);
      ffn2_gemm_db<<<dim3(DMODEL / 128, NTOK / 128), 256, 0, stream>>>(
          HbB, wdb, idx, cnt, out, dummy, e);
    }
  }
}